// Round 8
// baseline (25.616 us; speedup 1.0000x reference)
//
#include <hip/hip_runtime.h>
#include <hip/hip_bf16.h>

// LengthRegulator, single fused kernel, OUTPUT-partitioned, scatter-tok.
// out[b, j, :] = x[b, tok(j), :], tok(j) = searchsorted_right(csum, j) clipped.
//
// Grid: 16 batch rows x 32 windows = 512 blocks (exactly 2/CU); each block
// owns a fixed 128-row output window (192 KB contiguous). Per block:
//   1. scan: 256 threads load dur row (float4), wave shfl-scan + cross-wave
//      combine -> each scan thread holds its 4 tokens' csum in REGISTERS.
//   2. scatter: each scan thread writes tok[p-o0]=t for its intervals'
//      intersection with the window (intervals partition [0,T_OUT)).
//   3. uniform store loop: 32 iterations/thread in 8-deep load/store batches
//      (8 independent x-loads in flight hide read latency under the store
//      stream), nontemporal streaming stores, zero divergence.
// Preamble (dur load + scan) amortized over 2x stores vs the 64-row window.
// B=16, T=1024, D=384, T_OUT=4096 (fixed by the reference).

#define LR_B     16
#define LR_T     1024
#define LR_D4    96      // 384 floats = 96 float4 per row
#define LR_TOUT  4096
#define LR_WIN   128     // output rows per block
#define LR_NWIN  (LR_TOUT / LR_WIN)   // 32 windows per batch row
#define LR_NTHR  384     // 6 waves: 96 float4-lanes x 4 row-slot groups

typedef float lr_f4 __attribute__((ext_vector_type(4)));

__device__ __forceinline__ int lr_count(float d) {
    return (int)floorf(fmaxf(d, 0.0f) + 0.5f);
}

__global__ __launch_bounds__(LR_NTHR) void lr_fused(
    const float* __restrict__ dur, const lr_f4* __restrict__ x,
    lr_f4* __restrict__ out) {
    const int blk  = blockIdx.x;         // b * 32 + w
    const int b    = blk >> 5;
    const int w    = blk & (LR_NWIN - 1);
    const int o0   = w * LR_WIN;
    const int tid  = threadIdx.x;
    const int lane = tid & 63;
    const int wid  = tid >> 6;

    __shared__ int tok[LR_WIN];          // token index per output row in window
    __shared__ int wbase[4];             // per-wave scan partials (waves 0..3)

    // ---- phase 1: csum of row b, kept in scan-thread registers ----
    const lr_f4* drow4 = (const lr_f4*)(dur + b * LR_T);
    int c0 = 0, c1 = 0, c2 = 0, c3 = 0, s = 0;
    if (tid < LR_T / 4) {                // threads 0..255, one float4 each
        lr_f4 dv = drow4[tid];
        c0 = lr_count(dv.x);
        c1 = c0 + lr_count(dv.y);
        c2 = c1 + lr_count(dv.z);
        c3 = c2 + lr_count(dv.w);
        s = c3;
    }
    int v = s;                           // inclusive wave scan of thread sums
    #pragma unroll
    for (int off = 1; off < 64; off <<= 1) {
        int u = __shfl_up(v, off, 64);
        if (lane >= off) v += u;
    }
    if (tid < LR_T / 4 && lane == 63) wbase[wid] = v;
    __syncthreads();

    // ---- phase 2: scatter token ids into the window's tok[] table ----
    if (tid < LR_T / 4) {
        int base = v - s;                // exclusive prefix within wave
        #pragma unroll
        for (int ww = 0; ww < 4; ++ww)
            if (ww < wid) base += wbase[ww];
        int pr = base;                   // running interval start
        const int ends[4] = {base + c0, base + c1, base + c2, base + c3};
        #pragma unroll
        for (int k = 0; k < 4; ++k) {
            const int t = tid * 4 + k;
            int st = pr, en = ends[k];
            pr = en;
            if (t == LR_T - 1) en = LR_TOUT;   // tail: searchsorted+clip
            int lo = max(st, o0), hi = min(en, o0 + LR_WIN);
            for (int p = lo; p < hi; ++p) tok[p - o0] = t;
        }
    }
    __syncthreads();

    // ---- phase 3: uniform copy loop, 8-deep load/store batches ----
    const int g = tid / LR_D4;           // 0..3: row within 4-row slab
    const int d = tid - g * LR_D4;
    const lr_f4* xb = x + (size_t)b * LR_T * LR_D4 + d;
    lr_f4* ob = out + ((size_t)b * LR_TOUT + o0 + g) * LR_D4 + d;

    #pragma unroll
    for (int c = 0; c < LR_WIN / 4; c += 8) {
        lr_f4 vals[8];
        #pragma unroll
        for (int k = 0; k < 8; ++k) {
            const int t = tok[(c + k) * 4 + g];   // LDS broadcast per 96-lane group
            vals[k] = xb[(size_t)t * LR_D4];
        }
        #pragma unroll
        for (int k = 0; k < 8; ++k)
            __builtin_nontemporal_store(vals[k], &ob[(size_t)(c + k) * 4 * LR_D4]);
    }
}

extern "C" void kernel_launch(void* const* d_in, const int* in_sizes, int n_in,
                              void* d_out, int out_size, void* d_ws, size_t ws_size,
                              hipStream_t stream) {
    const float* x   = (const float*)d_in[0];   // [B, T, D] fp32
    const float* dur = (const float*)d_in[1];   // [B, T]    fp32
    // d_in[2] = out_len scalar (known: 4096)

    lr_fused<<<LR_B * LR_NWIN, LR_NTHR, 0, stream>>>(
        dur, (const lr_f4*)x, (lr_f4*)d_out);
}